// Round 3
// baseline (181.580 us; speedup 1.0000x reference)
//
#include <hip/hip_runtime.h>

typedef __attribute__((ext_vector_type(4))) float f32x4;
typedef __attribute__((ext_vector_type(8))) short short8;
typedef __attribute__((ext_vector_type(4))) unsigned int u32x4;
typedef unsigned short u16;
typedef unsigned int u32;
typedef unsigned long long u64;

__device__ __forceinline__ u16 f2bf(float f) {
  u32 u = __builtin_bit_cast(u32, f);
  u += 0x7fffu + ((u >> 16) & 1u);
  return (u16)(u >> 16);
}
__device__ __forceinline__ u16 f2bf_t(float f) {
  return (u16)(__builtin_bit_cast(u32, f) >> 16);
}

__device__ __forceinline__ void gl2lds16(const u16* g, const u16* l) {
  __builtin_amdgcn_global_load_lds(
      (const __attribute__((address_space(1))) u32*)g,
      (__attribute__((address_space(3))) u32*)(u32)(u64)l,
      16, 0, 0);
}

// ---------------------------------------------------------------------------
// Fused prep (unchanged): casts x/ctx to bf16, transposes+casts 3 weights.
// ---------------------------------------------------------------------------
__device__ __forceinline__ void cast_body(const float* __restrict__ s,
                                          u16* __restrict__ d, int blk,
                                          int tid) {
  long i = (long)blk * 256 + tid;
  const f32x4* sp = (const f32x4*)(s + i * 8);
  f32x4 a = sp[0], b = sp[1];
  u16 t[8];
#pragma unroll
  for (int j = 0; j < 4; j++) {
    t[j] = f2bf(a[j]);
    t[4 + j] = f2bf(b[j]);
  }
  *(u32x4*)(d + i * 8) = *(u32x4*)t;
}

__device__ __forceinline__ void transpose_body(const float* __restrict__ W,
                                               u16* __restrict__ WT, int K,
                                               int N, int k0, int n0, int tid,
                                               u16* T) {
#pragma unroll
  for (int i = 0; i < 4; i++) {
    int c = tid + 256 * i;
    int row = c >> 4;
    int ch = c & 15;
    f32x4 f = *(const f32x4*)(W + (long)(k0 + row) * N + n0 + ch * 4);
#pragma unroll
    for (int j = 0; j < 4; j++) T[(ch * 4 + j) * 72 + row] = f2bf(f[j]);
  }
  __syncthreads();
#pragma unroll
  for (int i = 0; i < 2; i++) {
    int c = tid + 256 * i;
    int row = c >> 3;
    int ch = c & 7;
    u32x4 v = *(u32x4*)&T[row * 72 + ch * 8];
    *(u32x4*)(WT + (long)(n0 + row) * K + k0 + ch * 8) = v;
  }
}

__global__ __launch_bounds__(256) void prep(
    const float* __restrict__ x, const float* __restrict__ ctx,
    const float* __restrict__ Wq, const float* __restrict__ Wkv,
    const float* __restrict__ Wo, u16* __restrict__ xb,
    u16* __restrict__ ctxb, u16* __restrict__ wqT, u16* __restrict__ wkvT,
    u16* __restrict__ woT) {
  __shared__ __align__(16) u16 T[64 * 72];
  const int b = blockIdx.x, tid = threadIdx.x;
  if (b < 2048) {
    cast_body(x, xb, b, tid);
  } else if (b < 3584) {
    cast_body(ctx, ctxb, b - 2048, tid);
  } else if (b < 3840) {
    int idx = b - 3584;
    transpose_body(Wq, wqT, 1024, 1024, (idx >> 4) * 64, (idx & 15) * 64, tid, T);
  } else if (b < 4224) {
    int idx = b - 3840;
    transpose_body(Wkv, wkvT, 768, 2048, (idx >> 5) * 64, (idx & 31) * 64, tid, T);
  } else {
    int idx = b - 4224;
    transpose_body(Wo, woT, 1024, 1024, (idx >> 4) * 64, (idx & 15) * 64, tid, T);
  }
}

// ---------------------------------------------------------------------------
// 128x128 GEMM core (m97-class), unchanged.
// ---------------------------------------------------------------------------
__device__ __forceinline__ void gemm128_core(
    const u16* __restrict__ A, const u16* __restrict__ Bt, int Kstride,
    int Klen, long brow, long bcol, int tid, u16* As, u16* Bs,
    f32x4 (&acc)[4][4]) {
  const int lane = tid & 63, wv = tid >> 6;
  const int l15 = lane & 15, quad = lane >> 4;
  const int wr = (wv >> 1) * 64, wc = (wv & 1) * 64;
  const int sr = lane >> 3, sc = lane & 7;
  const int csw = ((sc ^ sr) & 7) * 8;

  const u16* ag[4];
  const u16* bg[4];
  const u16* al[4];
  const u16* bl[4];
#pragma unroll
  for (int n = 0; n < 4; n++) {
    int row = wv * 32 + n * 8;
    ag[n] = A + (brow + row + sr) * (long)Kstride + csw;
    al[n] = &As[row * 64];
    bg[n] = Bt + (bcol + row + sr) * (long)Kstride + csw;
    bl[n] = &Bs[row * 64];
  }

  for (int kt = 0; kt < Klen; kt += 64) {
    __syncthreads();
#pragma unroll
    for (int n = 0; n < 4; n++) gl2lds16(ag[n] + kt, al[n]);
#pragma unroll
    for (int n = 0; n < 4; n++) gl2lds16(bg[n] + kt, bl[n]);
    __syncthreads();
#pragma unroll
    for (int kk = 0; kk < 2; kk++) {
      short8 af[4], bf[4];
#pragma unroll
      for (int i = 0; i < 4; i++) {
        int row = wr + i * 16 + l15;
        af[i] = *(short8*)&As[row * 64 + (((kk * 4 + quad) ^ (row & 7)) << 3)];
      }
#pragma unroll
      for (int j = 0; j < 4; j++) {
        int row = wc + j * 16 + l15;
        bf[j] = *(short8*)&Bs[row * 64 + (((kk * 4 + quad) ^ (row & 7)) << 3)];
      }
#pragma unroll
      for (int i = 0; i < 4; i++)
#pragma unroll
        for (int j = 0; j < 4; j++)
          acc[i][j] = __builtin_amdgcn_mfma_f32_16x16x32_bf16(
              af[i], bf[j], acc[i][j], 0, 0, 0);
    }
  }
}

// ---------------------------------------------------------------------------
// Fused Q-proj + KV-proj (unchanged). KV epilogue emits K and V in
// fragment-instruction-major global layout.
// ---------------------------------------------------------------------------
__global__ __launch_bounds__(256, 3) void fused_qkv(
    const u16* __restrict__ xb, const u16* __restrict__ ctxb,
    const u16* __restrict__ wqT, const u16* __restrict__ wkvT,
    u16* __restrict__ Qb, u16* __restrict__ Kfrag, u16* __restrict__ Vfrag,
    float qscale) {
  __shared__ __align__(16) u16 As[128 * 64];
  __shared__ __align__(16) u16 Bs[128 * 64];
  const int tid = threadIdx.x;
  const int lane = tid & 63, wv = tid >> 6;
  const int l15 = lane & 15, quad = lane >> 4;
  const int wr = (wv >> 1) * 64, wc = (wv & 1) * 64;

  f32x4 acc[4][4];
#pragma unroll
  for (int i = 0; i < 4; i++)
#pragma unroll
    for (int j = 0; j < 4; j++) acc[i][j] = (f32x4){0.f, 0.f, 0.f, 0.f};

  int bid = blockIdx.x;
  if (bid < 256) {
    long brow = (long)(bid >> 3) * 128, bcol = (long)(bid & 7) * 128;
    gemm128_core(xb, wqT, 1024, 1024, brow, bcol, tid, As, Bs, acc);
#pragma unroll
    for (int i = 0; i < 4; i++)
#pragma unroll
      for (int j = 0; j < 4; j++)
#pragma unroll
        for (int r = 0; r < 4; r++) {
          long row = brow + wr + i * 16 + quad * 4 + r;
          long col = bcol + wc + j * 16 + l15;
          Qb[row * 1024 + col] = f2bf(acc[i][j][r] * qscale);
        }
    return;
  }

  bid -= 256;
  long brow = (long)(bid >> 4) * 128, bcol = (long)(bid & 15) * 128;
  gemm128_core(ctxb, wkvT, 768, 768, brow, bcol, tid, As, Bs, acc);

  const bool is_k = (bcol < 1024);
  __syncthreads();  // all frag reads of As/Bs done; reuse As as transpose buf
#pragma unroll
  for (int round = 0; round < 2; round++) {
    if ((wv >> 1) == round) {
      if (is_k) {
#pragma unroll
        for (int i = 0; i < 4; i++)
#pragma unroll
          for (int j = 0; j < 4; j++) {
            int d = j * 16 + l15;
            int off = (wv & 1) * 4096 + ((d >> 5) * 4 + i) * 512 +
                      (((d >> 3) & 3) * 16 + quad * 4) * 8 + (d & 7);
#pragma unroll
            for (int r = 0; r < 4; r++) As[off + r * 8] = f2bf(acc[i][j][r]);
          }
      } else {
#pragma unroll
        for (int i = 0; i < 4; i++)
#pragma unroll
          for (int j = 0; j < 4; j++) {
            int off = (wv & 1) * 4096 + ((i >> 1) * 4 + j) * 512 +
                      (quad * 16 + l15) * 8 + (i & 1) * 4;
            u16 t4[4];
#pragma unroll
            for (int r = 0; r < 4; r++) t4[r] = f2bf(acc[i][j][r]);
            *(u64*)&As[off] = *(const u64*)t4;
          }
      }
    }
    __syncthreads();
    long mg = brow + round * 64;
    int b_ = (int)(mg >> 11), mt = (int)((mg >> 6) & 31);
#pragma unroll
    for (int h2 = 0; h2 < 2; h2++) {
      int h = (int)((is_k ? bcol : bcol - 1024) >> 6) + h2;
      u16* dst = (is_k ? Kfrag : Vfrag) + ((long)(b_ * 16 + h) * 32 + mt) * 4096;
#pragma unroll
      for (int p = 0; p < 2; p++) {
        int c = p * 256 + tid;  // 0..511 chunks of 16B
        *(u32x4*)(dst + c * 8) = *(u32x4*)&As[h2 * 4096 + c * 8];
      }
    }
    __syncthreads();
  }
}

// ---------------------------------------------------------------------------
// O-projection GEMM (unchanged). 128x128 tiles.
// ---------------------------------------------------------------------------
__global__ __launch_bounds__(256, 3) void gemm_o(
    const u16* __restrict__ A, const u16* __restrict__ Bt,
    float* __restrict__ C) {
  __shared__ __align__(16) u16 As[128 * 64];
  __shared__ __align__(16) u16 Bs[128 * 64];
  const int tid = threadIdx.x;
  const int lane = tid & 63, wv = tid >> 6;
  const int l15 = lane & 15, quad = lane >> 4;
  const int wr = (wv >> 1) * 64, wc = (wv & 1) * 64;
  long brow = (long)blockIdx.y * 128, bcol = (long)blockIdx.x * 128;

  f32x4 acc[4][4];
#pragma unroll
  for (int i = 0; i < 4; i++)
#pragma unroll
    for (int j = 0; j < 4; j++) acc[i][j] = (f32x4){0.f, 0.f, 0.f, 0.f};

  gemm128_core(A, Bt, 1024, 1024, brow, bcol, tid, As, Bs, acc);

#pragma unroll
  for (int i = 0; i < 4; i++)
#pragma unroll
    for (int j = 0; j < 4; j++)
#pragma unroll
      for (int r = 0; r < 4; r++) {
        long row = brow + wr + i * 16 + quad * 4 + r;
        long col = bcol + wc + j * 16 + l15;
        C[row * 1024 + col] = acc[i][j][r];
      }
}

// ---------------------------------------------------------------------------
// Flash attention v9: counted-vmcnt software pipeline (T3+T4) + setprio (T5)
// + v_perm bf16 packing.
// 512 threads = 8 waves; wave w: q-chunk (w&3), KV-half (w>>2) — unchanged.
// KV now consumed in 32 steps of 32 rows each; per step 16KB staged into a
// 4-deep LDS ring (64KB total, 2 blocks/CU). Prefetch depth 3; per step:
//   s_waitcnt vmcnt(4)  (never 0 in steady state)  ->  s_barrier
//   -> issue stage(s+3) -> ds_read K -> 8 QK MFMA -> exp2+perm-pack
//   -> ds_read V -> 10 PV MFMA.
// Epilogue drains vmcnt 4 -> 2 -> 0 (steps 29/30/31). Stage chunk c=2w,2w+1
// per wave; vmcnt counting relies on every wave issuing exactly 2 loads per
// stage. "memory"-clobbered asm pins load ordering across the barrier.
// ---------------------------------------------------------------------------
__global__ __launch_bounds__(512, 4) void attn_kernel(
    const u16* __restrict__ Q, const u16* __restrict__ Kfrag,
    const u16* __restrict__ Vfrag, u16* __restrict__ AO) {
  __shared__ __align__(16) u16 smem[4][8192];  // 4-ring of 16KB steps
  const int tid = threadIdx.x;
  const int lane = tid & 63, wv = tid >> 6;
  const int qc = wv & 3, half = wv >> 2;
  const int l15 = lane & 15, quad = lane >> 4;
  const int bh = blockIdx.y;
  const int b = bh >> 4, h = bh & 15;
  const long qrow0 = (long)b * 2048 + blockIdx.x * 128 + qc * 32;

  short8 qf[2][2];
#pragma unroll
  for (int qt = 0; qt < 2; qt++)
#pragma unroll
    for (int kk = 0; kk < 2; kk++)
      qf[qt][kk] = *(const short8*)&Q[(qrow0 + qt * 16 + l15) * 1024 +
                                      h * 64 + kk * 32 + quad * 8];

  f32x4 O[2][5];
#pragma unroll
  for (int qt = 0; qt < 2; qt++)
#pragma unroll
    for (int dt = 0; dt < 5; dt++) O[qt][dt] = (f32x4){0.f, 0.f, 0.f, 0.f};

  u32x4 ones_u = {0x3F803F80u, 0x3F803F80u, 0x3F803F80u, 0x3F803F80u};
  short8 ones = __builtin_bit_cast(short8, ones_u);

  const u16* kg0 = Kfrag + (long)bh * 32 * 4096;
  const u16* vg0 = Vfrag + (long)bh * 32 * 4096;

  // step s (0..31): tile = s>>1, 32-row group g = s&1, both KV-halves.
  // step buffer layout (16 x 1KB chunks): c 0-3 K(half0) [kk*2+tt],
  // 4-7 V(half0) [dt], 8-11 K(half1), 12-15 V(half1).
  // wave w stages chunks 2w, 2w+1 (2 gl2lds = the vmcnt unit).
  auto stage = [&](int s) {
#pragma unroll
    for (int u = 0; u < 2; u++) {
      int c = wv * 2 + u;
      int g3 = c >> 2, idx = c & 3;
      int hh = g3 >> 1;
      const u16* src;
      if ((g3 & 1) == 0) {  // K: chunks kk*4 + g*2 + tt of tile
        int kk = idx >> 1, tt = idx & 1;
        src = kg0 + (long)(hh * 16 + (s >> 1)) * 4096 +
              (kk * 4 + (s & 1) * 2 + tt) * 512 + lane * 8;
      } else {  // V: chunks g*4 + dt of tile
        src = vg0 + (long)(hh * 16 + (s >> 1)) * 4096 +
              ((s & 1) * 4 + idx) * 512 + lane * 8;
      }
      gl2lds16(src, &smem[s & 3][c * 512]);
    }
  };

  stage(0);
  stage(1);
  stage(2);  // 6 loads/wave in flight (+4 Q loads, drained at step 0)

  for (int s = 0; s < 32; s++) {
    if (s < 30)
      asm volatile("s_waitcnt vmcnt(4)" ::: "memory");
    else if (s == 30)
      asm volatile("s_waitcnt vmcnt(2)" ::: "memory");
    else
      asm volatile("s_waitcnt vmcnt(0)" ::: "memory");
    __builtin_amdgcn_s_barrier();
    asm volatile("" ::: "memory");  // no LDS reads hoist above the barrier
    if (s + 3 < 32) stage(s + 3);

    const u16* rb = &smem[s & 3][0];
    const u16* Ks = rb + half * 4096 + lane * 8;
    const u16* Vs = rb + half * 4096 + 2048 + lane * 8;

    // S^T = K @ Q^T for 32 KV rows (2 m-subtiles x 2 q-tiles)
    short8 kf[2][2];
#pragma unroll
    for (int kk = 0; kk < 2; kk++)
#pragma unroll
      for (int tt = 0; tt < 2; tt++)
        kf[kk][tt] = *(const short8*)(Ks + (kk * 2 + tt) * 512);
    f32x4 sacc[2][2];
#pragma unroll
    for (int tt = 0; tt < 2; tt++)
#pragma unroll
      for (int qt = 0; qt < 2; qt++) sacc[tt][qt] = (f32x4){0.f, 0.f, 0.f, 0.f};
    __builtin_amdgcn_s_setprio(1);
#pragma unroll
    for (int kk = 0; kk < 2; kk++)
#pragma unroll
      for (int tt = 0; tt < 2; tt++)
#pragma unroll
        for (int qt = 0; qt < 2; qt++)
          sacc[tt][qt] = __builtin_amdgcn_mfma_f32_16x16x32_bf16(
              kf[kk][tt], qf[qt][kk], sacc[tt][qt], 0, 0, 0);
    __builtin_amdgcn_s_setprio(0);

    // p = exp2(s-24); pack two bf16 truncations per word with one v_perm
    short8 pa[2];
#pragma unroll
    for (int qt = 0; qt < 2; qt++) {
      u32 w[4];
#pragma unroll
      for (int tt = 0; tt < 2; tt++) {
        f32x4 sv = sacc[tt][qt];
        u32 e0 = __builtin_bit_cast(u32, __builtin_amdgcn_exp2f(sv[0] - 24.f));
        u32 e1 = __builtin_bit_cast(u32, __builtin_amdgcn_exp2f(sv[1] - 24.f));
        u32 e2 = __builtin_bit_cast(u32, __builtin_amdgcn_exp2f(sv[2] - 24.f));
        u32 e3 = __builtin_bit_cast(u32, __builtin_amdgcn_exp2f(sv[3] - 24.f));
        w[tt * 2] = __builtin_amdgcn_perm(e1, e0, 0x07060302u);
        w[tt * 2 + 1] = __builtin_amdgcn_perm(e3, e2, 0x07060302u);
      }
      pa[qt] = __builtin_bit_cast(short8, *(u32x4*)w);
    }

    // O += P @ V  (+ rowsum via ones)
    short8 vf[4];
#pragma unroll
    for (int dt = 0; dt < 4; dt++)
      vf[dt] = *(const short8*)(Vs + dt * 512);
    __builtin_amdgcn_s_setprio(1);
#pragma unroll
    for (int qt = 0; qt < 2; qt++) {
#pragma unroll
      for (int dt = 0; dt < 4; dt++)
        O[qt][dt] = __builtin_amdgcn_mfma_f32_16x16x32_bf16(
            pa[qt], vf[dt], O[qt][dt], 0, 0, 0);
      O[qt][4] = __builtin_amdgcn_mfma_f32_16x16x32_bf16(
          pa[qt], ones, O[qt][4], 0, 0, 0);
    }
    __builtin_amdgcn_s_setprio(0);
  }

  // ---- combine the two KV-halves (linear: O and rowsum just add) ----
  // cb spans smem[0..2] (40KB); step-31 readers touch only smem[3] -> safe.
  f32x4* cb = (f32x4*)&smem[0][0];
  if (half) {
#pragma unroll
    for (int qt = 0; qt < 2; qt++)
#pragma unroll
      for (int dt = 0; dt < 5; dt++)
        cb[(qc * 64 + lane) * 10 + qt * 5 + dt] = O[qt][dt];
  }
  __syncthreads();
  if (!half) {
#pragma unroll
    for (int qt = 0; qt < 2; qt++)
#pragma unroll
      for (int dt = 0; dt < 5; dt++)
        O[qt][dt] += cb[(qc * 64 + lane) * 10 + qt * 5 + dt];

#pragma unroll
    for (int qt = 0; qt < 2; qt++) {
      float inv[4];
#pragma unroll
      for (int r = 0; r < 4; r++) inv[r] = 1.f / O[qt][4][r];
#pragma unroll
      for (int dt = 0; dt < 4; dt++)
#pragma unroll
        for (int r = 0; r < 4; r++) {
          long row = qrow0 + qt * 16 + quad * 4 + r;
          int col = h * 64 + dt * 16 + l15;
          AO[row * 1024 + col] = f2bf(O[qt][dt][r] * inv[r]);
        }
    }
  }
}

// ---------------------------------------------------------------------------
extern "C" void kernel_launch(void* const* d_in, const int* in_sizes, int n_in,
                              void* d_out, int out_size, void* d_ws,
                              size_t ws_size, hipStream_t stream) {
  const float* x = (const float*)d_in[0];     // [2,2048,1024]
  const float* ctx = (const float*)d_in[1];   // [2,2048,768]
  const float* Wq = (const float*)d_in[2];    // [1024,1024]
  const float* Wkv = (const float*)d_in[3];   // [768,2048]
  const float* Wo = (const float*)d_in[4];    // [1024,1024]
  float* out = (float*)d_out;                 // [2,2048,1024] fp32

  u16* ws = (u16*)d_ws;
  u16* wqT = ws;                       // [1024][1024]
  u16* wkvT = wqT + 1048576;           // [2048][768]
  u16* woT = wkvT + 1572864;           // [1024][1024]
  u16* Qb = woT + 1048576;             // [4096][1024] bf16 (q-scaled)
  u16* Kfrag = Qb + 4194304;           // [32][32][4096] fragment-major K
  u16* Vfrag = Kfrag + 4194304;        // [32][32][4096] fragment-major V
  u16* xb = Vfrag + 4194304;           // [4096][1024] bf16 (aliased: AOb)
  u16* ctxb = xb + 4194304;            // [4096][768]  bf16
  u16* AOb = xb;  // xb dead after fused_qkv

  const float qscale = 0.125f * 1.4426950408889634f;  // Dh^-0.5 * log2(e)

  prep<<<dim3(4480), 256, 0, stream>>>(x, ctx, Wq, Wkv, Wo, xb, ctxb, wqT,
                                       wkvT, woT);

  fused_qkv<<<dim3(768), 256, 0, stream>>>(xb, ctxb, wqT, wkvT, Qb, Kfrag,
                                           Vfrag, qscale);

  attn_kernel<<<dim3(16, 32), 512, 0, stream>>>(Qb, Kfrag, Vfrag, AOb);

  gemm_o<<<dim3(8, 32), 256, 0, stream>>>(AOb, woT, out);
}

// Round 4
// 169.871 us; speedup vs baseline: 1.0689x; 1.0689x over previous
//
#include <hip/hip_runtime.h>

typedef __attribute__((ext_vector_type(4))) float f32x4;
typedef __attribute__((ext_vector_type(8))) short short8;
typedef __attribute__((ext_vector_type(4))) unsigned int u32x4;
typedef unsigned short u16;
typedef unsigned int u32;
typedef unsigned long long u64;

__device__ __forceinline__ u16 f2bf(float f) {
  u32 u = __builtin_bit_cast(u32, f);
  u += 0x7fffu + ((u >> 16) & 1u);
  return (u16)(u >> 16);
}

__device__ __forceinline__ void gl2lds16(const u16* g, const u16* l) {
  __builtin_amdgcn_global_load_lds(
      (const __attribute__((address_space(1))) u32*)g,
      (__attribute__((address_space(3))) u32*)(u32)(u64)l,
      16, 0, 0);
}

// ---------------------------------------------------------------------------
// Fused prep (unchanged): casts x/ctx to bf16, transposes+casts 3 weights.
// ---------------------------------------------------------------------------
__device__ __forceinline__ void cast_body(const float* __restrict__ s,
                                          u16* __restrict__ d, int blk,
                                          int tid) {
  long i = (long)blk * 256 + tid;
  const f32x4* sp = (const f32x4*)(s + i * 8);
  f32x4 a = sp[0], b = sp[1];
  u16 t[8];
#pragma unroll
  for (int j = 0; j < 4; j++) {
    t[j] = f2bf(a[j]);
    t[4 + j] = f2bf(b[j]);
  }
  *(u32x4*)(d + i * 8) = *(u32x4*)t;
}

__device__ __forceinline__ void transpose_body(const float* __restrict__ W,
                                               u16* __restrict__ WT, int K,
                                               int N, int k0, int n0, int tid,
                                               u16* T) {
#pragma unroll
  for (int i = 0; i < 4; i++) {
    int c = tid + 256 * i;
    int row = c >> 4;
    int ch = c & 15;
    f32x4 f = *(const f32x4*)(W + (long)(k0 + row) * N + n0 + ch * 4);
#pragma unroll
    for (int j = 0; j < 4; j++) T[(ch * 4 + j) * 72 + row] = f2bf(f[j]);
  }
  __syncthreads();
#pragma unroll
  for (int i = 0; i < 2; i++) {
    int c = tid + 256 * i;
    int row = c >> 3;
    int ch = c & 7;
    u32x4 v = *(u32x4*)&T[row * 72 + ch * 8];
    *(u32x4*)(WT + (long)(n0 + row) * K + k0 + ch * 8) = v;
  }
}

__global__ __launch_bounds__(256) void prep(
    const float* __restrict__ x, const float* __restrict__ ctx,
    const float* __restrict__ Wq, const float* __restrict__ Wkv,
    const float* __restrict__ Wo, u16* __restrict__ xb,
    u16* __restrict__ ctxb, u16* __restrict__ wqT, u16* __restrict__ wkvT,
    u16* __restrict__ woT) {
  __shared__ __align__(16) u16 T[64 * 72];
  const int b = blockIdx.x, tid = threadIdx.x;
  if (b < 2048) {
    cast_body(x, xb, b, tid);
  } else if (b < 3584) {
    cast_body(ctx, ctxb, b - 2048, tid);
  } else if (b < 3840) {
    int idx = b - 3584;
    transpose_body(Wq, wqT, 1024, 1024, (idx >> 4) * 64, (idx & 15) * 64, tid, T);
  } else if (b < 4224) {
    int idx = b - 3840;
    transpose_body(Wkv, wkvT, 768, 2048, (idx >> 5) * 64, (idx & 31) * 64, tid, T);
  } else {
    int idx = b - 4224;
    transpose_body(Wo, woT, 1024, 1024, (idx >> 4) * 64, (idx & 15) * 64, tid, T);
  }
}

// ---------------------------------------------------------------------------
// 128x128 GEMM core (m97-class), unchanged.
// ---------------------------------------------------------------------------
__device__ __forceinline__ void gemm128_core(
    const u16* __restrict__ A, const u16* __restrict__ Bt, int Kstride,
    int Klen, long brow, long bcol, int tid, u16* As, u16* Bs,
    f32x4 (&acc)[4][4]) {
  const int lane = tid & 63, wv = tid >> 6;
  const int l15 = lane & 15, quad = lane >> 4;
  const int wr = (wv >> 1) * 64, wc = (wv & 1) * 64;
  const int sr = lane >> 3, sc = lane & 7;
  const int csw = ((sc ^ sr) & 7) * 8;

  const u16* ag[4];
  const u16* bg[4];
  const u16* al[4];
  const u16* bl[4];
#pragma unroll
  for (int n = 0; n < 4; n++) {
    int row = wv * 32 + n * 8;
    ag[n] = A + (brow + row + sr) * (long)Kstride + csw;
    al[n] = &As[row * 64];
    bg[n] = Bt + (bcol + row + sr) * (long)Kstride + csw;
    bl[n] = &Bs[row * 64];
  }

  for (int kt = 0; kt < Klen; kt += 64) {
    __syncthreads();
#pragma unroll
    for (int n = 0; n < 4; n++) gl2lds16(ag[n] + kt, al[n]);
#pragma unroll
    for (int n = 0; n < 4; n++) gl2lds16(bg[n] + kt, bl[n]);
    __syncthreads();
#pragma unroll
    for (int kk = 0; kk < 2; kk++) {
      short8 af[4], bf[4];
#pragma unroll
      for (int i = 0; i < 4; i++) {
        int row = wr + i * 16 + l15;
        af[i] = *(short8*)&As[row * 64 + (((kk * 4 + quad) ^ (row & 7)) << 3)];
      }
#pragma unroll
      for (int j = 0; j < 4; j++) {
        int row = wc + j * 16 + l15;
        bf[j] = *(short8*)&Bs[row * 64 + (((kk * 4 + quad) ^ (row & 7)) << 3)];
      }
#pragma unroll
      for (int i = 0; i < 4; i++)
#pragma unroll
        for (int j = 0; j < 4; j++)
          acc[i][j] = __builtin_amdgcn_mfma_f32_16x16x32_bf16(
              af[i], bf[j], acc[i][j], 0, 0, 0);
    }
  }
}

// ---------------------------------------------------------------------------
// Fused Q-proj + KV-proj (unchanged). KV epilogue emits K and V in
// fragment-instruction-major global layout.
// ---------------------------------------------------------------------------
__global__ __launch_bounds__(256, 3) void fused_qkv(
    const u16* __restrict__ xb, const u16* __restrict__ ctxb,
    const u16* __restrict__ wqT, const u16* __restrict__ wkvT,
    u16* __restrict__ Qb, u16* __restrict__ Kfrag, u16* __restrict__ Vfrag,
    float qscale) {
  __shared__ __align__(16) u16 As[128 * 64];
  __shared__ __align__(16) u16 Bs[128 * 64];
  const int tid = threadIdx.x;
  const int lane = tid & 63, wv = tid >> 6;
  const int l15 = lane & 15, quad = lane >> 4;
  const int wr = (wv >> 1) * 64, wc = (wv & 1) * 64;

  f32x4 acc[4][4];
#pragma unroll
  for (int i = 0; i < 4; i++)
#pragma unroll
    for (int j = 0; j < 4; j++) acc[i][j] = (f32x4){0.f, 0.f, 0.f, 0.f};

  int bid = blockIdx.x;
  if (bid < 256) {
    long brow = (long)(bid >> 3) * 128, bcol = (long)(bid & 7) * 128;
    gemm128_core(xb, wqT, 1024, 1024, brow, bcol, tid, As, Bs, acc);
#pragma unroll
    for (int i = 0; i < 4; i++)
#pragma unroll
      for (int j = 0; j < 4; j++)
#pragma unroll
        for (int r = 0; r < 4; r++) {
          long row = brow + wr + i * 16 + quad * 4 + r;
          long col = bcol + wc + j * 16 + l15;
          Qb[row * 1024 + col] = f2bf(acc[i][j][r] * qscale);
        }
    return;
  }

  bid -= 256;
  long brow = (long)(bid >> 4) * 128, bcol = (long)(bid & 15) * 128;
  gemm128_core(ctxb, wkvT, 768, 768, brow, bcol, tid, As, Bs, acc);

  const bool is_k = (bcol < 1024);
  __syncthreads();  // all frag reads of As/Bs done; reuse As as transpose buf
#pragma unroll
  for (int round = 0; round < 2; round++) {
    if ((wv >> 1) == round) {
      if (is_k) {
#pragma unroll
        for (int i = 0; i < 4; i++)
#pragma unroll
          for (int j = 0; j < 4; j++) {
            int d = j * 16 + l15;
            int off = (wv & 1) * 4096 + ((d >> 5) * 4 + i) * 512 +
                      (((d >> 3) & 3) * 16 + quad * 4) * 8 + (d & 7);
#pragma unroll
            for (int r = 0; r < 4; r++) As[off + r * 8] = f2bf(acc[i][j][r]);
          }
      } else {
#pragma unroll
        for (int i = 0; i < 4; i++)
#pragma unroll
          for (int j = 0; j < 4; j++) {
            int off = (wv & 1) * 4096 + ((i >> 1) * 4 + j) * 512 +
                      (quad * 16 + l15) * 8 + (i & 1) * 4;
            u16 t4[4];
#pragma unroll
            for (int r = 0; r < 4; r++) t4[r] = f2bf(acc[i][j][r]);
            *(u64*)&As[off] = *(const u64*)t4;
          }
      }
    }
    __syncthreads();
    long mg = brow + round * 64;
    int b_ = (int)(mg >> 11), mt = (int)((mg >> 6) & 31);
#pragma unroll
    for (int h2 = 0; h2 < 2; h2++) {
      int h = (int)((is_k ? bcol : bcol - 1024) >> 6) + h2;
      u16* dst = (is_k ? Kfrag : Vfrag) + ((long)(b_ * 16 + h) * 32 + mt) * 4096;
#pragma unroll
      for (int p = 0; p < 2; p++) {
        int c = p * 256 + tid;  // 0..511 chunks of 16B
        *(u32x4*)(dst + c * 8) = *(u32x4*)&As[h2 * 4096 + c * 8];
      }
    }
    __syncthreads();
  }
}

// ---------------------------------------------------------------------------
// O-projection GEMM (unchanged). 128x128 tiles.
// ---------------------------------------------------------------------------
__global__ __launch_bounds__(256, 3) void gemm_o(
    const u16* __restrict__ A, const u16* __restrict__ Bt,
    float* __restrict__ C) {
  __shared__ __align__(16) u16 As[128 * 64];
  __shared__ __align__(16) u16 Bs[128 * 64];
  const int tid = threadIdx.x;
  const int lane = tid & 63, wv = tid >> 6;
  const int l15 = lane & 15, quad = lane >> 4;
  const int wr = (wv >> 1) * 64, wc = (wv & 1) * 64;
  long brow = (long)blockIdx.y * 128, bcol = (long)blockIdx.x * 128;

  f32x4 acc[4][4];
#pragma unroll
  for (int i = 0; i < 4; i++)
#pragma unroll
    for (int j = 0; j < 4; j++) acc[i][j] = (f32x4){0.f, 0.f, 0.f, 0.f};

  gemm128_core(A, Bt, 1024, 1024, brow, bcol, tid, As, Bs, acc);

#pragma unroll
  for (int i = 0; i < 4; i++)
#pragma unroll
    for (int j = 0; j < 4; j++)
#pragma unroll
      for (int r = 0; r < 4; r++) {
        long row = brow + wr + i * 16 + quad * 4 + r;
        long col = bcol + wc + j * 16 + l15;
        C[row * 1024 + col] = acc[i][j][r];
      }
}

// ---------------------------------------------------------------------------
// Flash attention v10 = v8 structure (16 iters, 2-buffer LDS, 44.8us proven)
// + VALU diet:
//  - exp2(s) with NO -24 shift: the fixed power-of-2 scale cancels exactly in
//    O/rowsum (pure exponent shift; mantissas identical) -> saves 32 subs/iter
//  - zero-C MFMA: first-kk QK MFMA reads persistent zero regs as C instead of
//    re-zeroing 8 accumulators per iter -> saves 32 v_mov/iter
//  - v_perm_b32 bf16 pair packing (1 op/pair, validated in v9)
//  - s_setprio(1) around MFMA clusters
// VALU was the critical pipe (3205 cyc/iter/SIMD vs MFMA 2400); this cuts
// ~900 cyc/iter/SIMD of VALU.
// grid (16, 32), block 512 (8 waves: q-chunk w&3, KV-half w>>2).
// ---------------------------------------------------------------------------
__global__ __launch_bounds__(512, 4) void attn_kernel(
    const u16* __restrict__ Q, const u16* __restrict__ Kfrag,
    const u16* __restrict__ Vfrag, u16* __restrict__ AO) {
  __shared__ __align__(16) u16 smem[2][4][4096];  // [buf][K0,V0,K1,V1][tile]
  const int tid = threadIdx.x;
  const int lane = tid & 63, wv = tid >> 6;
  const int qc = wv & 3, half = wv >> 2;
  const int l15 = lane & 15, quad = lane >> 4;
  const int bh = blockIdx.y;
  const int b = bh >> 4, h = bh & 15;
  const long qrow0 = (long)b * 2048 + blockIdx.x * 128 + qc * 32;

  short8 qf[2][2];
#pragma unroll
  for (int qt = 0; qt < 2; qt++)
#pragma unroll
    for (int kk = 0; kk < 2; kk++)
      qf[qt][kk] = *(const short8*)&Q[(qrow0 + qt * 16 + l15) * 1024 +
                                      h * 64 + kk * 32 + quad * 8];

  f32x4 O[2][5];
#pragma unroll
  for (int qt = 0; qt < 2; qt++)
#pragma unroll
    for (int dt = 0; dt < 5; dt++) O[qt][dt] = (f32x4){0.f, 0.f, 0.f, 0.f};

  u32x4 ones_u = {0x3F803F80u, 0x3F803F80u, 0x3F803F80u, 0x3F803F80u};
  short8 ones = __builtin_bit_cast(short8, ones_u);
  const f32x4 z4 = {0.f, 0.f, 0.f, 0.f};  // persistent zero C-operand

  // staging: each wave covers u16 [wv*512, wv*512+512) of each 8KB chunk
  const u16* kg0 = Kfrag + (long)bh * 32 * 4096;
  const u16* vg0 = Vfrag + (long)bh * 32 * 4096;
  const int so = wv * 512 + lane * 8;

  auto stage = [&](int nb, int i) {
    const u16* k0 = kg0 + (long)i * 4096 + so;
    const u16* v0 = vg0 + (long)i * 4096 + so;
    gl2lds16(k0, &smem[nb][0][wv * 512]);
    gl2lds16(v0, &smem[nb][1][wv * 512]);
    gl2lds16(k0 + 16 * 4096, &smem[nb][2][wv * 512]);
    gl2lds16(v0 + 16 * 4096, &smem[nb][3][wv * 512]);
  };

  stage(0, 0);
  __syncthreads();  // implicit vmcnt(0): buf0 staged

  for (int i = 0; i < 16; i++) {
    const int cur = i & 1;
    if (i < 15) stage(cur ^ 1, i + 1);  // overlap next-tile DMA with compute

    const u16* Ks = &smem[cur][half * 2][0] + lane * 8;
    const u16* Vs = &smem[cur][half * 2 + 1][0] + lane * 8;

    // S^T = K @ Q^T (rows m, cols q). kk=0 uses zero-C (no acc re-init).
    f32x4 s[4][2];
    {
      short8 kf[4];
#pragma unroll
      for (int t = 0; t < 4; t++) kf[t] = *(const short8*)(Ks + t * 512);
      __builtin_amdgcn_s_setprio(1);
#pragma unroll
      for (int m4 = 0; m4 < 4; m4++)
#pragma unroll
        for (int qt = 0; qt < 2; qt++)
          s[m4][qt] = __builtin_amdgcn_mfma_f32_16x16x32_bf16(
              kf[m4], qf[qt][0], z4, 0, 0, 0);
      __builtin_amdgcn_s_setprio(0);
    }
    {
      short8 kf[4];
#pragma unroll
      for (int t = 0; t < 4; t++) kf[t] = *(const short8*)(Ks + (4 + t) * 512);
      __builtin_amdgcn_s_setprio(1);
#pragma unroll
      for (int m4 = 0; m4 < 4; m4++)
#pragma unroll
        for (int qt = 0; qt < 2; qt++)
          s[m4][qt] = __builtin_amdgcn_mfma_f32_16x16x32_bf16(
              kf[m4], qf[qt][1], s[m4][qt], 0, 0, 0);
      __builtin_amdgcn_s_setprio(0);
    }

    // p = exp2(s); perm-pack pairs straight into PV A-fragments; O += P @ V
#pragma unroll
    for (int kk = 0; kk < 2; kk++) {
      short8 vf[4];
#pragma unroll
      for (int dt = 0; dt < 4; dt++)
        vf[dt] = *(const short8*)(Vs + (kk * 4 + dt) * 512);
#pragma unroll
      for (int qt = 0; qt < 2; qt++) {
        u32 w[4];
#pragma unroll
        for (int hw = 0; hw < 2; hw++) {
          f32x4 sv = s[2 * kk + hw][qt];
          u32 e0 = __builtin_bit_cast(u32, __builtin_amdgcn_exp2f(sv[0]));
          u32 e1 = __builtin_bit_cast(u32, __builtin_amdgcn_exp2f(sv[1]));
          u32 e2 = __builtin_bit_cast(u32, __builtin_amdgcn_exp2f(sv[2]));
          u32 e3 = __builtin_bit_cast(u32, __builtin_amdgcn_exp2f(sv[3]));
          w[hw * 2] = __builtin_amdgcn_perm(e1, e0, 0x07060302u);
          w[hw * 2 + 1] = __builtin_amdgcn_perm(e3, e2, 0x07060302u);
        }
        short8 pa = __builtin_bit_cast(short8, *(u32x4*)w);
        __builtin_amdgcn_s_setprio(1);
#pragma unroll
        for (int dt = 0; dt < 4; dt++)
          O[qt][dt] = __builtin_amdgcn_mfma_f32_16x16x32_bf16(
              pa, vf[dt], O[qt][dt], 0, 0, 0);
        O[qt][4] = __builtin_amdgcn_mfma_f32_16x16x32_bf16(
            pa, ones, O[qt][4], 0, 0, 0);
        __builtin_amdgcn_s_setprio(0);
      }
    }
    __syncthreads();  // drains stage DMA; all reads of smem[cur] done
  }

  // ---- combine the two KV-halves (linear: O and rowsum just add) ----
  f32x4* cb = (f32x4*)&smem[0][0][0];  // 40 KB of the 64 KB buffer
  if (half) {
#pragma unroll
    for (int qt = 0; qt < 2; qt++)
#pragma unroll
      for (int dt = 0; dt < 5; dt++)
        cb[(qc * 64 + lane) * 10 + qt * 5 + dt] = O[qt][dt];
  }
  __syncthreads();
  if (!half) {
#pragma unroll
    for (int qt = 0; qt < 2; qt++)
#pragma unroll
      for (int dt = 0; dt < 5; dt++)
        O[qt][dt] += cb[(qc * 64 + lane) * 10 + qt * 5 + dt];

#pragma unroll
    for (int qt = 0; qt < 2; qt++) {
      float inv[4];
#pragma unroll
      for (int r = 0; r < 4; r++) inv[r] = 1.f / O[qt][4][r];
#pragma unroll
      for (int dt = 0; dt < 4; dt++)
#pragma unroll
        for (int r = 0; r < 4; r++) {
          long row = qrow0 + qt * 16 + quad * 4 + r;
          int col = h * 64 + dt * 16 + l15;
          AO[row * 1024 + col] = f2bf(O[qt][dt][r] * inv[r]);
        }
    }
  }
}

// ---------------------------------------------------------------------------
extern "C" void kernel_launch(void* const* d_in, const int* in_sizes, int n_in,
                              void* d_out, int out_size, void* d_ws,
                              size_t ws_size, hipStream_t stream) {
  const float* x = (const float*)d_in[0];     // [2,2048,1024]
  const float* ctx = (const float*)d_in[1];   // [2,2048,768]
  const float* Wq = (const float*)d_in[2];    // [1024,1024]
  const float* Wkv = (const float*)d_in[3];   // [768,2048]
  const float* Wo = (const float*)d_in[4];    // [1024,1024]
  float* out = (float*)d_out;                 // [2,2048,1024] fp32

  u16* ws = (u16*)d_ws;
  u16* wqT = ws;                       // [1024][1024]
  u16* wkvT = wqT + 1048576;           // [2048][768]
  u16* woT = wkvT + 1572864;           // [1024][1024]
  u16* Qb = woT + 1048576;             // [4096][1024] bf16 (q-scaled)
  u16* Kfrag = Qb + 4194304;           // [32][32][4096] fragment-major K
  u16* Vfrag = Kfrag + 4194304;        // [32][32][4096] fragment-major V
  u16* xb = Vfrag + 4194304;           // [4096][1024] bf16 (aliased: AOb)
  u16* ctxb = xb + 4194304;            // [4096][768]  bf16
  u16* AOb = xb;  // xb dead after fused_qkv

  const float qscale = 0.125f * 1.4426950408889634f;  // Dh^-0.5 * log2(e)

  prep<<<dim3(4480), 256, 0, stream>>>(x, ctx, Wq, Wkv, Wo, xb, ctxb, wqT,
                                       wkvT, woT);

  fused_qkv<<<dim3(768), 256, 0, stream>>>(xb, ctxb, wqT, wkvT, Qb, Kfrag,
                                           Vfrag, qscale);

  attn_kernel<<<dim3(16, 32), 512, 0, stream>>>(Qb, Kfrag, Vfrag, AOb);

  gemm_o<<<dim3(8, 32), 256, 0, stream>>>(AOb, woT, out);
}